// Round 3
// 852.445 us; speedup vs baseline: 1.0133x; 1.0133x over previous
//
#include <hip/hip_runtime.h>

#define BQ 64        // batch (query rows)
#define MB 256       // bank entries (sim columns)
#define DK 524288    // feature dim (K)
#define SS 2048      // style dim
#define CH 16        // K-chunk depth per staging iteration
#define TPB 256
#define NCHUNK (DK / CH)   // 32768 chunks

// ---------------------------------------------------------------------------
// K1: fused partial matmul + column sum-of-squares.
//   sim_raw[b,m] = sum_d content[b*DK+d] * bank[d*MB+m]   (ct = raw reshape!)
//   cn[m]       = sum_d bank[d*MB+m]^2
// Double-buffered LDS, register-staged (T14 issue-early/write-late):
//   iter i: issue global loads for chunk i+1 -> regs, compute chunk i from
//   LDS, then ds_write regs into the other buffer, one barrier. HBM latency
//   hides under the 8x8xCH FMA block (~2k cy/wave). cn is fused into the
//   write phase (each chunk written exactly once: prologue or as some
//   iteration's "next"), same accumulation order as before.
// ---------------------------------------------------------------------------
__global__ __launch_bounds__(TPB, 4) void k1_partial(
    const float* __restrict__ content, const float* __restrict__ bank,
    float* __restrict__ psim, float* __restrict__ pcn, int G)
{
    __shared__ float ct_t[2][CH * MB];   // [buf][d][m]  2 x 16 KB
    __shared__ float cs_t[2][CH * BQ];   // [buf][d][b]  2 x 4 KB
    const int tid = threadIdx.x;
    const int g   = blockIdx.x;
    const int tb  = tid & 7;          // b-tile: b = tb*8 + i
    const int tm  = tid >> 3;         // m-tile: m = tm*8 + j

    float acc[8][8];
    #pragma unroll
    for (int i = 0; i < 8; ++i)
        #pragma unroll
        for (int j = 0; j < 8; ++j) acc[i][j] = 0.f;
    // thread's staged ct float4 slots all cover m-quad (tid&63)*4 .. +3
    float cn0 = 0.f, cn1 = 0.f, cn2 = 0.f, cn3 = 0.f;

    // staging geometry (constant per thread)
    const float4* bank4 = (const float4*)bank;           // chunk c = 1024 slots
    const int csb_b  = tid >> 2;                  // 0..63  (query row)
    const int csb_c4 = tid & 3;                   // 0..3   (d-quad within chunk)
    const float* cs_src = content + (size_t)csb_b * DK + csb_c4 * 4;

    float4 rct0, rct1, rct2, rct3;    // in-flight ct chunk (16 VGPR)
    float4 rcs;                       // in-flight cs chunk (4 VGPR)

    // ---- prologue: load + write chunk g into buffer 0 ----
    {
        const size_t base = (size_t)g * 1024 + tid;
        rct0 = bank4[base];           rct1 = bank4[base + 256];
        rct2 = bank4[base + 512];     rct3 = bank4[base + 768];
        rcs  = *(const float4*)(cs_src + (size_t)g * CH);
    }
    {
        float4* dst = (float4*)ct_t[0];
        dst[tid]       = rct0;  dst[tid + 256] = rct1;
        dst[tid + 512] = rct2;  dst[tid + 768] = rct3;
        cn0 = fmaf(rct0.x, rct0.x, cn0); cn1 = fmaf(rct0.y, rct0.y, cn1);
        cn2 = fmaf(rct0.z, rct0.z, cn2); cn3 = fmaf(rct0.w, rct0.w, cn3);
        cn0 = fmaf(rct1.x, rct1.x, cn0); cn1 = fmaf(rct1.y, rct1.y, cn1);
        cn2 = fmaf(rct1.z, rct1.z, cn2); cn3 = fmaf(rct1.w, rct1.w, cn3);
        cn0 = fmaf(rct2.x, rct2.x, cn0); cn1 = fmaf(rct2.y, rct2.y, cn1);
        cn2 = fmaf(rct2.z, rct2.z, cn2); cn3 = fmaf(rct2.w, rct2.w, cn3);
        cn0 = fmaf(rct3.x, rct3.x, cn0); cn1 = fmaf(rct3.y, rct3.y, cn1);
        cn2 = fmaf(rct3.z, rct3.z, cn2); cn3 = fmaf(rct3.w, rct3.w, cn3);
        const int dd = csb_c4 * 4;
        cs_t[0][(dd + 0) * BQ + csb_b] = rcs.x;
        cs_t[0][(dd + 1) * BQ + csb_b] = rcs.y;
        cs_t[0][(dd + 2) * BQ + csb_b] = rcs.z;
        cs_t[0][(dd + 3) * BQ + csb_b] = rcs.w;
    }
    __syncthreads();

    int cur = 0;
    for (int c = g; c < NCHUNK; c += G) {
        const int nxt = c + G;
        const bool have = (nxt < NCHUNK);
        if (have) {                    // issue-early: loads overlap compute
            const size_t base = (size_t)nxt * 1024 + tid;
            rct0 = bank4[base];           rct1 = bank4[base + 256];
            rct2 = bank4[base + 512];     rct3 = bank4[base + 768];
            rcs  = *(const float4*)(cs_src + (size_t)nxt * CH);
        }
        // ---- 8x8 register-tile outer product over the chunk ----
        const float* csb = cs_t[cur];
        const float* ctb = ct_t[cur];
        #pragma unroll 2
        for (int d = 0; d < CH; ++d) {
            float4 a0 = *(const float4*)&csb[d * BQ + tb * 8];
            float4 a1 = *(const float4*)&csb[d * BQ + tb * 8 + 4];
            float4 b0 = *(const float4*)&ctb[d * MB + tm * 8];
            float4 b1 = *(const float4*)&ctb[d * MB + tm * 8 + 4];
            float av[8] = {a0.x, a0.y, a0.z, a0.w, a1.x, a1.y, a1.z, a1.w};
            float bv[8] = {b0.x, b0.y, b0.z, b0.w, b1.x, b1.y, b1.z, b1.w};
            #pragma unroll
            for (int i = 0; i < 8; ++i)
                #pragma unroll
                for (int j = 0; j < 8; ++j)
                    acc[i][j] = fmaf(av[i], bv[j], acc[i][j]);
        }
        // ---- write-late: next chunk into the other buffer + fused cn ----
        if (have) {
            float4* dst = (float4*)ct_t[cur ^ 1];
            dst[tid]       = rct0;  dst[tid + 256] = rct1;
            dst[tid + 512] = rct2;  dst[tid + 768] = rct3;
            cn0 = fmaf(rct0.x, rct0.x, cn0); cn1 = fmaf(rct0.y, rct0.y, cn1);
            cn2 = fmaf(rct0.z, rct0.z, cn2); cn3 = fmaf(rct0.w, rct0.w, cn3);
            cn0 = fmaf(rct1.x, rct1.x, cn0); cn1 = fmaf(rct1.y, rct1.y, cn1);
            cn2 = fmaf(rct1.z, rct1.z, cn2); cn3 = fmaf(rct1.w, rct1.w, cn3);
            cn0 = fmaf(rct2.x, rct2.x, cn0); cn1 = fmaf(rct2.y, rct2.y, cn1);
            cn2 = fmaf(rct2.z, rct2.z, cn2); cn3 = fmaf(rct2.w, rct2.w, cn3);
            cn0 = fmaf(rct3.x, rct3.x, cn0); cn1 = fmaf(rct3.y, rct3.y, cn1);
            cn2 = fmaf(rct3.z, rct3.z, cn2); cn3 = fmaf(rct3.w, rct3.w, cn3);
            const int dd = csb_c4 * 4;
            float* dcs = cs_t[cur ^ 1];
            dcs[(dd + 0) * BQ + csb_b] = rcs.x;
            dcs[(dd + 1) * BQ + csb_b] = rcs.y;
            dcs[(dd + 2) * BQ + csb_b] = rcs.z;
            dcs[(dd + 3) * BQ + csb_b] = rcs.w;
        }
        __syncthreads();   // next buffer fully staged; all reads of cur done
        cur ^= 1;
    }

    // ---- flush sim partial tile ----
    {
        float* outp = psim + (size_t)g * (BQ * MB);
        #pragma unroll
        for (int i = 0; i < 8; ++i) {
            int b = tb * 8 + i;
            *(float4*)&outp[b * MB + tm * 8] =
                make_float4(acc[i][0], acc[i][1], acc[i][2], acc[i][3]);
            *(float4*)&outp[b * MB + tm * 8 + 4] =
                make_float4(acc[i][4], acc[i][5], acc[i][6], acc[i][7]);
        }
    }
    // ---- flush colnorm partial: LDS transpose-reduce (reuse ct_t[0]) ----
    __syncthreads();
    *(float4*)&ct_t[0][tid * 4] = make_float4(cn0, cn1, cn2, cn3);
    __syncthreads();
    {
        int m = tid;                       // 0..255
        int tsrc = m >> 2, comp = m & 3;   // contributors: tsrc + 64*w
        float v = ct_t[0][(tsrc      ) * 4 + comp]
                + ct_t[0][(tsrc +  64) * 4 + comp]
                + ct_t[0][(tsrc + 128) * 4 + comp]
                + ct_t[0][(tsrc + 192) * 4 + comp];
        pcn[(size_t)g * MB + m] = v;
    }
}

// ---------------------------------------------------------------------------
// K2: reduce G partials -> 8 partials (deterministic, no atomics).
// 16640 outputs (16384 sim + 256 cn) x 8 g-stripes; 520 blocks of 256.
// ---------------------------------------------------------------------------
__global__ void k2_reduce(const float* __restrict__ psim,
                          const float* __restrict__ pcn,
                          float* __restrict__ stage2, int G)
{
    const int r  = blockIdx.x % 65;
    const int gs = blockIdx.x / 65;
    const int o  = r * 256 + threadIdx.x;   // 0..16639
    float s = 0.f;
    if (o < BQ * MB) {
        for (int g = gs; g < G; g += 8) s += psim[(size_t)g * (BQ * MB) + o];
    } else {
        int m = o - BQ * MB;
        for (int g = gs; g < G; g += 8) s += pcn[(size_t)g * MB + m];
    }
    stage2[(size_t)gs * 16640 + o] = s;
}

// ---------------------------------------------------------------------------
// K3: per-row argmax (numpy first-index tie-break) + style-row gather.
// Query-side norm is a positive per-row scale -> skipped (argmax-invariant).
// ---------------------------------------------------------------------------
__global__ void k3_argmax_gather(const float* __restrict__ stage2,
                                 const float* __restrict__ bank_style,
                                 float* __restrict__ out)
{
    const int b = blockIdx.x;
    const int tid = threadIdx.x;          // == m
    float s = 0.f, c = 0.f;
    #pragma unroll
    for (int gs = 0; gs < 8; ++gs) {
        s += stage2[(size_t)gs * 16640 + b * MB + tid];
        c += stage2[(size_t)gs * 16640 + BQ * MB + tid];
    }
    float score = s / fmaxf(sqrtf(c), 1e-12f);

    float best = score; int bidx = tid;
    #pragma unroll
    for (int off = 32; off >= 1; off >>= 1) {   // wave64 reduce
        float os = __shfl_down(best, off);
        int   oi = __shfl_down(bidx, off);
        if (os > best || (os == best && oi < bidx)) { best = os; bidx = oi; }
    }
    __shared__ float wbest[4];
    __shared__ int   widx[4];
    __shared__ int   fidx;
    int wave = tid >> 6, lane = tid & 63;
    if (lane == 0) { wbest[wave] = best; widx[wave] = bidx; }
    __syncthreads();
    if (tid == 0) {
        float fb = wbest[0]; int fi = widx[0];
        #pragma unroll
        for (int w = 1; w < 4; ++w)
            if (wbest[w] > fb || (wbest[w] == fb && widx[w] < fi)) {
                fb = wbest[w]; fi = widx[w];
            }
        fidx = fi;
    }
    __syncthreads();
    const float4* srcr = (const float4*)(bank_style + (size_t)fidx * SS);
    float4*       dstr = (float4*)(out + (size_t)b * SS);
    for (int k = tid; k < SS / 4; k += TPB) dstr[k] = srcr[k];
}

// ---------------------------------------------------------------------------
extern "C" void kernel_launch(void* const* d_in, const int* in_sizes, int n_in,
                              void* d_out, int out_size, void* d_ws, size_t ws_size,
                              hipStream_t stream)
{
    const float* content      = (const float*)d_in[0];
    const float* bank_content = (const float*)d_in[1];
    const float* bank_style   = (const float*)d_in[2];
    float* out = (float*)d_out;

    // ws layout: psim[G][16384] | pcn[G][256] | stage2[8][16640]
    long long avail = (long long)(ws_size / 4) - 8LL * 16640;
    int G = (int)(avail / 16640);
    if (G > 1024) G = 1024;   // 4 blocks/CU on 256 CUs (LDS: 40 KB/block)
    if (G < 1)    G = 1;

    float* psim   = (float*)d_ws;
    float* pcn    = psim + (size_t)G * (BQ * MB);
    float* stage2 = psim + (size_t)G * 16640;

    k1_partial<<<G, TPB, 0, stream>>>(content, bank_content, psim, pcn, G);
    k2_reduce<<<520, TPB, 0, stream>>>(psim, pcn, stage2, G);
    k3_argmax_gather<<<BQ, TPB, 0, stream>>>(stage2, bank_style, out);
}

// Round 4
// 821.584 us; speedup vs baseline: 1.0514x; 1.0376x over previous
//
#include <hip/hip_runtime.h>

#define BQ 64        // batch (query rows)
#define MB 256       // bank entries (sim columns)
#define DK 524288    // feature dim (K)
#define SS 2048      // style dim
#define CH 32        // K-chunk depth = one MFMA K-step
#define TPB 256
#define NCHUNK (DK / CH)   // 16384 chunks

#define SA 40        // A-plane LDS row stride (32 k + 8 pad) -> 80 B rows, 16B-aligned
#define SB 260       // B-plane LDS row stride (256 m + 4 pad) -> 520 B rows

typedef __attribute__((ext_vector_type(8))) short short8;
typedef __attribute__((ext_vector_type(4))) float f32x4;

__device__ __forceinline__ unsigned short bf16_rne(float x) {
    unsigned int u = __float_as_uint(x);
    return (unsigned short)((u + 0x7FFFu + ((u >> 16) & 1u)) >> 16);
}
__device__ __forceinline__ float bf16_f32(unsigned short h) {
    return __uint_as_float((unsigned int)h << 16);
}

// ---------------------------------------------------------------------------
// K1: fused partial matmul + column sum-of-squares, via split-bf16 MFMA.
//   sim_raw[b,m] = sum_d content[b*DK+d] * bank[d*MB+m]   (ct = raw reshape!)
//   cn[m]       = sum_d bank[d*MB+m]^2   (EXACT fp32, fused at staging)
// Each fp32 x is split x = hi + lo (bf16 RNE hi, bf16 lo of residual);
// sim accumulates ah*bh + al*bh + ah*bl in fp32 MFMA accumulators —
// dropped lo*lo term is ~2^-18 |a||b| per element: score error ~1.5e-5,
// same order as fp32 reordering noise (argmax gaps ~0.34). Compute cost
// collapses to ~21 us total -> k1 is pure HBM streaming (~720 MB).
// Per block: 4 waves; wave w owns m in [64w,64w+64) = 4 col-tiles; all 4
// row-tiles of b. acc[bt][mt] = 16 tiles of 16x16, 3 MFMA each per chunk.
// ---------------------------------------------------------------------------
__global__ __launch_bounds__(TPB, 2) void k1_partial(
    const float* __restrict__ content, const float* __restrict__ bank,
    float* __restrict__ psim, float* __restrict__ pcn, int G)
{
    __shared__ unsigned short A_hi[BQ * SA];   // [b][k]  5.0 KB
    __shared__ unsigned short A_lo[BQ * SA];   //         5.0 KB
    __shared__ unsigned short B_hi[CH * SB];   // [k][m] 16.25 KB
    __shared__ unsigned short B_lo[CH * SB];   //        16.25 KB
    __shared__ float cnscr[TPB * 4];           //         4.0 KB

    const int tid  = threadIdx.x;
    const int g    = blockIdx.x;
    const int w    = tid >> 6;        // wave 0..3
    const int l    = tid & 63;        // lane
    const int rowl = l & 15;          // MFMA frag row (A) / col (B,C)
    const int kg   = l >> 4;          // MFMA frag k-group (k = kg*8 + j)

    f32x4 acc[4][4];                  // [bt][mt]
    #pragma unroll
    for (int i = 0; i < 4; ++i)
        #pragma unroll
        for (int j = 0; j < 4; ++j) acc[i][j] = (f32x4){0.f, 0.f, 0.f, 0.f};

    float cn0 = 0.f, cn1 = 0.f, cn2 = 0.f, cn3 = 0.f;

    const float4* bank4 = (const float4*)bank;     // chunk = 2048 float4
    float4 rb[8];     // in-flight bank chunk: slot tid+256q -> d = w+4q (wave-uniform), m0 = 4l
    float4 rc[2];     // in-flight content: q -> b = 8w+32q+(l>>3), dquad = l&7

    auto load_chunk = [&](int c) {
        const float4* bsrc = bank4 + (size_t)c * (CH * MB / 4);
        #pragma unroll
        for (int q = 0; q < 8; ++q) rb[q] = bsrc[tid + (q << 8)];
        #pragma unroll
        for (int q = 0; q < 2; ++q) {
            const int b = (w << 3) + (q << 5) + (l >> 3);
            rc[q] = *(const float4*)(content + (size_t)b * DK
                                     + (size_t)c * CH + ((l & 7) << 2));
        }
    };
    auto store_chunk = [&]() {
        #pragma unroll
        for (int q = 0; q < 8; ++q) {
            const int d = w + (q << 2);
            const float4 v = rb[q];
            const unsigned short h0 = bf16_rne(v.x), h1 = bf16_rne(v.y),
                                 h2 = bf16_rne(v.z), h3 = bf16_rne(v.w);
            const unsigned short e0 = bf16_rne(v.x - bf16_f32(h0)),
                                 e1 = bf16_rne(v.y - bf16_f32(h1)),
                                 e2 = bf16_rne(v.z - bf16_f32(h2)),
                                 e3 = bf16_rne(v.w - bf16_f32(h3));
            *(short4*)&B_hi[d * SB + (l << 2)] =
                make_short4((short)h0, (short)h1, (short)h2, (short)h3);
            *(short4*)&B_lo[d * SB + (l << 2)] =
                make_short4((short)e0, (short)e1, (short)e2, (short)e3);
            cn0 = fmaf(v.x, v.x, cn0);  cn1 = fmaf(v.y, v.y, cn1);
            cn2 = fmaf(v.z, v.z, cn2);  cn3 = fmaf(v.w, v.w, cn3);
        }
        #pragma unroll
        for (int q = 0; q < 2; ++q) {
            const int b = (w << 3) + (q << 5) + (l >> 3);
            const float4 v = rc[q];
            const unsigned short h0 = bf16_rne(v.x), h1 = bf16_rne(v.y),
                                 h2 = bf16_rne(v.z), h3 = bf16_rne(v.w);
            const unsigned short e0 = bf16_rne(v.x - bf16_f32(h0)),
                                 e1 = bf16_rne(v.y - bf16_f32(h1)),
                                 e2 = bf16_rne(v.z - bf16_f32(h2)),
                                 e3 = bf16_rne(v.w - bf16_f32(h3));
            *(short4*)&A_hi[b * SA + ((l & 7) << 2)] =
                make_short4((short)h0, (short)h1, (short)h2, (short)h3);
            *(short4*)&A_lo[b * SA + ((l & 7) << 2)] =
                make_short4((short)e0, (short)e1, (short)e2, (short)e3);
        }
    };

    // ---- prologue: stage first chunk ----
    load_chunk(g);
    store_chunk();
    __syncthreads();

    for (int c = g; c < NCHUNK; c += G) {
        const int nxt = c + G;
        const bool have = (nxt < NCHUNK);
        if (have) load_chunk(nxt);       // issue-early: overlaps compute

        #pragma unroll
        for (int mt = 0; mt < 4; ++mt) {
            const int colo = (w << 6) + (mt << 4) + rowl;
            short8 bhv, blv;
            #pragma unroll
            for (int j = 0; j < 8; ++j) {
                const int ro = ((kg << 3) + j) * SB + colo;
                bhv[j] = (short)B_hi[ro];
                blv[j] = (short)B_lo[ro];
            }
            #pragma unroll
            for (int bt = 0; bt < 4; ++bt) {
                const int ao = ((bt << 4) + rowl) * SA + (kg << 3);
                const short8 ahv = *(const short8*)&A_hi[ao];
                const short8 alv = *(const short8*)&A_lo[ao];
                acc[bt][mt] = __builtin_amdgcn_mfma_f32_16x16x32_bf16(
                                  ahv, bhv, acc[bt][mt], 0, 0, 0);
                acc[bt][mt] = __builtin_amdgcn_mfma_f32_16x16x32_bf16(
                                  alv, bhv, acc[bt][mt], 0, 0, 0);
                acc[bt][mt] = __builtin_amdgcn_mfma_f32_16x16x32_bf16(
                                  ahv, blv, acc[bt][mt], 0, 0, 0);
            }
        }
        __syncthreads();                 // all LDS reads of chunk c done
        if (have) store_chunk();         // write-late: hi/lo split + cn fma
        __syncthreads();                 // chunk nxt staged
    }

    // ---- flush sim partial tile (C layout: col=lane&15, row=kg*4+i) ----
    {
        float* outp = psim + (size_t)g * (BQ * MB);
        #pragma unroll
        for (int bt = 0; bt < 4; ++bt)
            #pragma unroll
            for (int mt = 0; mt < 4; ++mt) {
                const int m = (w << 6) + (mt << 4) + rowl;
                #pragma unroll
                for (int i = 0; i < 4; ++i) {
                    const int b = (bt << 4) + (kg << 2) + i;
                    outp[b * MB + m] = acc[bt][mt][i];
                }
            }
    }
    // ---- flush colnorm partial: transpose-reduce over the 4 waves ----
    *(float4*)&cnscr[tid * 4] = make_float4(cn0, cn1, cn2, cn3);
    __syncthreads();
    {
        const int m = tid;                      // 0..255
        const int tsrc = m >> 2, comp = m & 3;  // contributors: tsrc + 64*w
        float v = cnscr[(tsrc      ) * 4 + comp]
                + cnscr[(tsrc +  64) * 4 + comp]
                + cnscr[(tsrc + 128) * 4 + comp]
                + cnscr[(tsrc + 192) * 4 + comp];
        pcn[(size_t)g * MB + m] = v;
    }
}

// ---------------------------------------------------------------------------
// K2: reduce G partials -> 8 partials (deterministic, no atomics).
// 16640 outputs (16384 sim + 256 cn) x 8 g-stripes; 520 blocks of 256.
// ---------------------------------------------------------------------------
__global__ void k2_reduce(const float* __restrict__ psim,
                          const float* __restrict__ pcn,
                          float* __restrict__ stage2, int G)
{
    const int r  = blockIdx.x % 65;
    const int gs = blockIdx.x / 65;
    const int o  = r * 256 + threadIdx.x;   // 0..16639
    float s = 0.f;
    if (o < BQ * MB) {
        for (int g = gs; g < G; g += 8) s += psim[(size_t)g * (BQ * MB) + o];
    } else {
        int m = o - BQ * MB;
        for (int g = gs; g < G; g += 8) s += pcn[(size_t)g * MB + m];
    }
    stage2[(size_t)gs * 16640 + o] = s;
}

// ---------------------------------------------------------------------------
// K3: per-row argmax (numpy first-index tie-break) + style-row gather.
// Query-side norm is a positive per-row scale -> skipped (argmax-invariant).
// ---------------------------------------------------------------------------
__global__ void k3_argmax_gather(const float* __restrict__ stage2,
                                 const float* __restrict__ bank_style,
                                 float* __restrict__ out)
{
    const int b = blockIdx.x;
    const int tid = threadIdx.x;          // == m
    float s = 0.f, c = 0.f;
    #pragma unroll
    for (int gs = 0; gs < 8; ++gs) {
        s += stage2[(size_t)gs * 16640 + b * MB + tid];
        c += stage2[(size_t)gs * 16640 + BQ * MB + tid];
    }
    float score = s / fmaxf(sqrtf(c), 1e-12f);

    float best = score; int bidx = tid;
    #pragma unroll
    for (int off = 32; off >= 1; off >>= 1) {   // wave64 reduce
        float os = __shfl_down(best, off);
        int   oi = __shfl_down(bidx, off);
        if (os > best || (os == best && oi < bidx)) { best = os; bidx = oi; }
    }
    __shared__ float wbest[4];
    __shared__ int   widx[4];
    __shared__ int   fidx;
    int wave = tid >> 6, lane = tid & 63;
    if (lane == 0) { wbest[wave] = best; widx[wave] = bidx; }
    __syncthreads();
    if (tid == 0) {
        float fb = wbest[0]; int fi = widx[0];
        #pragma unroll
        for (int w = 1; w < 4; ++w)
            if (wbest[w] > fb || (wbest[w] == fb && widx[w] < fi)) {
                fb = wbest[w]; fi = widx[w];
            }
        fidx = fi;
    }
    __syncthreads();
    const float4* srcr = (const float4*)(bank_style + (size_t)fidx * SS);
    float4*       dstr = (float4*)(out + (size_t)b * SS);
    for (int k = tid; k < SS / 4; k += TPB) dstr[k] = srcr[k];
}

// ---------------------------------------------------------------------------
extern "C" void kernel_launch(void* const* d_in, const int* in_sizes, int n_in,
                              void* d_out, int out_size, void* d_ws, size_t ws_size,
                              hipStream_t stream)
{
    const float* content      = (const float*)d_in[0];
    const float* bank_content = (const float*)d_in[1];
    const float* bank_style   = (const float*)d_in[2];
    float* out = (float*)d_out;

    // ws layout: psim[G][16384] | pcn[G][256] | stage2[8][16640]
    long long avail = (long long)(ws_size / 4) - 8LL * 16640;
    int G = (int)(avail / 16640);
    if (G > 768) G = 768;   // 3 blocks/CU on 256 CUs (47.6 KB LDS each)
    if (G < 1)   G = 1;

    float* psim   = (float*)d_ws;
    float* pcn    = psim + (size_t)G * (BQ * MB);
    float* stage2 = psim + (size_t)G * 16640;

    k1_partial<<<G, TPB, 0, stream>>>(content, bank_content, psim, pcn, G);
    k2_reduce<<<520, TPB, 0, stream>>>(psim, pcn, stage2, G);
    k3_argmax_gather<<<BQ, TPB, 0, stream>>>(stage2, bank_style, out);
}